// Round 8
// baseline (281.731 us; speedup 1.0000x reference)
//
#include <hip/hip_runtime.h>

#define NH 12
#define HD 64
#define SEQ 1024
#define BATCH 8
#define DIM 768
#define QKVN 2304
#define ROWS 8192   // BATCH*SEQ

typedef __bf16 bf16x8 __attribute__((ext_vector_type(8)));
typedef float f32x4 __attribute__((ext_vector_type(4)));
typedef unsigned short u16x8 __attribute__((ext_vector_type(8)));
typedef unsigned short u16x4 __attribute__((ext_vector_type(4)));
typedef short s16x4 __attribute__((ext_vector_type(4)));

__device__ __forceinline__ unsigned short f2bf(float f) {
  union { float f; unsigned int u; } c; c.f = f;
  unsigned int u = c.u;
  u += 0x7fffu + ((u >> 16) & 1u);   // RNE; inputs are normal floats
  return (unsigned short)(u >> 16);
}

__device__ __forceinline__ void gload_lds16(const unsigned short* g, unsigned short* l) {
  __builtin_amdgcn_global_load_lds(
      (const __attribute__((address_space(1))) void*)g,
      (__attribute__((address_space(3))) void*)l, 16, 0, 0);
}

// ---------------- fused prep: f32->bf16 cast + both weight transposes ----------------
__device__ __forceinline__ void tr_tile(const float* __restrict__ src, unsigned short* __restrict__ dst,
                                        int R, int C, int bx, int by, float tile[32][33]) {
  int tx = threadIdx.x & 31, ty = threadIdx.x >> 5;   // 32 x 8
  int c0 = bx * 32, r0 = by * 32;
#pragma unroll
  for (int i = 0; i < 4; ++i)
    tile[ty + i * 8][tx] = src[(size_t)(r0 + ty + i * 8) * C + c0 + tx];
  __syncthreads();
#pragma unroll
  for (int i = 0; i < 4; ++i)
    dst[(size_t)(c0 + ty + i * 8) * R + r0 + tx] = f2bf(tile[tx][ty + i * 8]);
}

__global__ void prep_kernel(const float* __restrict__ x, unsigned short* __restrict__ xb,
                            const float* __restrict__ w_qkv, unsigned short* __restrict__ wqkvT,
                            const float* __restrict__ w_proj, unsigned short* __restrict__ wprojT) {
  __shared__ float tile[32][33];
  int blk = blockIdx.x;
  if (blk < 6144) {
    int i = blk * 256 + threadIdx.x;   // n4 = 8192*768/4 = 1572864 = 6144*256 exactly
    float4 v = ((const float4*)x)[i];
    u16x4 o;
    o.x = f2bf(v.x); o.y = f2bf(v.y); o.z = f2bf(v.z); o.w = f2bf(v.w);
    ((u16x4*)xb)[i] = o;
  } else if (blk < 6144 + 1728) {
    int t = blk - 6144;                // w_qkv: 768x2304 -> 24 x 72 tiles
    tr_tile(w_qkv, wqkvT, DIM, QKVN, t % 72, t / 72, tile);
  } else {
    int t = blk - 6144 - 1728;         // w_proj: 768x768 -> 24 x 24 tiles
    tr_tile(w_proj, wprojT, DIM, DIM, t % 24, t / 24, tile);
  }
}

// ---------------- LDS-free 128x128 bf16 GEMM, BT input, K templated ----------------
// No __syncthreads in the K-loop at all: every MFMA fragment is a contiguous 16 B
// global load (row-major, frag = row*K + quad*8 + kt*32). Fully-unrolled K-loop ->
// compiler interleaves MFMA <-> global_load with fine-grained vmcnt (the AITER
// pattern that LDS staging's barrier-vmcnt(0)-drain cannot express). Fragment
// duplication across the 2x2 wave grid is absorbed by L1/L2 (XCD-banded rows).
template <bool BF16_OUT, bool SCALE_Q, int K>
__global__ __launch_bounds__(256, 3) void gemm_reg(
    const unsigned short* __restrict__ A, const unsigned short* __restrict__ BT,
    void* __restrict__ Cout, const float* __restrict__ bias,
    int M, int N, int nbyXCD) {
  const int tid = threadIdx.x;
  const int wave = tid >> 6, lane = tid & 63, quad = lane >> 4, l16 = lane & 15;
  const int wm = wave >> 1, wn = wave & 1;
  const int g = blockIdx.x & 7, bi = blockIdx.x >> 3;
  const int by = g * nbyXCD + (bi % nbyXCD);
  const int bx = bi / nbyXCD;
  const int bm = by * 128, bn = bx * 128;

  // per-lane fragment base pointers (kt advances via imm offset: kt*64 B <= 1472)
  const unsigned short* Ap = A + (size_t)(bm + wm * 64 + l16) * K + quad * 8;
  const unsigned short* Bp = BT + (size_t)(bn + wn * 64 + l16) * K + quad * 8;

  f32x4 zero4 = {0.f, 0.f, 0.f, 0.f};
  f32x4 acc[4][4];
#pragma unroll
  for (int i = 0; i < 4; ++i)
#pragma unroll
    for (int j = 0; j < 4; ++j) acc[i][j] = zero4;

#pragma unroll
  for (int kt = 0; kt < K / 32; ++kt) {
    bf16x8 af[4], bf[4];
#pragma unroll
    for (int mt = 0; mt < 4; ++mt)
      af[mt] = *(const bf16x8*)(Ap + (size_t)mt * 16 * K + kt * 32);
#pragma unroll
    for (int nt = 0; nt < 4; ++nt)
      bf[nt] = *(const bf16x8*)(Bp + (size_t)nt * 16 * K + kt * 32);
#pragma unroll
    for (int mt = 0; mt < 4; ++mt)
#pragma unroll
      for (int nt = 0; nt < 4; ++nt)
        acc[mt][nt] = __builtin_amdgcn_mfma_f32_16x16x32_bf16(af[mt], bf[nt], acc[mt][nt], 0, 0, 0);
  }

#pragma unroll
  for (int mt = 0; mt < 4; ++mt)
#pragma unroll
    for (int nt = 0; nt < 4; ++nt) {
      int col = bn + wn * 64 + nt * 16 + l16;
      float bv = BF16_OUT ? 0.f : bias[col];
      float scl = (SCALE_Q && col < DIM) ? 0.125f : 1.0f;  // fold attn scale into q
#pragma unroll
      for (int r = 0; r < 4; ++r) {
        int row = bm + wm * 64 + mt * 16 + quad * 4 + r;
        float v = acc[mt][nt][r];
        if (BF16_OUT)
          ((unsigned short*)Cout)[(size_t)row * N + col] = f2bf(v * scl);
        else
          ((float*)Cout)[(size_t)row * N + col] = v + bv;
      }
    }
}

// ---------------- flash attention: Q-tile 128 (8 waves), KV-tile 64 ----------------
// S^T trick: scores computed transposed so exp(P) feeds PV directly from registers
// (C-layout [key=quad*4+r][query=l16] == A-frag of mfma_f32_16x16x16bf16_1k).
// Double-buffered K (DMA) + V (reg-held loads, LDS write sunk after compute): 1 barrier/jt.
#define VS 76   // Vts row stride (u16): 38 dwords == 6 mod 32 -> ~2-way (free) on b64 reads
__global__ __launch_bounds__(512, 6) void attn_kernel(
    const unsigned short* __restrict__ qkv, unsigned short* __restrict__ out) {
  __shared__ unsigned short Ks[2][64 * 64];     // [kk][n][32] split layout per buffer, 8 KB each
  __shared__ unsigned short Vts[2][64 * VS];    // V^T [d][n], 9.5 KB each

  const int tid = threadIdx.x;
  const int wave = tid >> 6, lane = tid & 63, quad = lane >> 4, l16 = lane & 15;
  // XCD-locality swizzle: all 8 q-tiles of one (b,h) share id%8 -> same XCD
  const int x = blockIdx.x;
  const int qt = (x >> 3) & 7;
  const int bh = (x & 7) + 8 * (x >> 6);
  const int b = bh / NH, h = bh % NH;
  const int qcol = h * HD, kcol = DIM + h * HD, vcol = 2 * DIM + h * HD;
  const int rowQ0 = b * SEQ + qt * 128;
  const int rowKV0 = b * SEQ;

  // staging index precompute
  const int kk_s = tid >> 8, rem_s = tid & 255, n_s = rem_s >> 2, kc_s = rem_s & 3;
  const unsigned short* kgp = qkv + (size_t)(rowKV0 + n_s) * QKVN + kcol + kk_s * 32 + kc_s * 8;
  unsigned short* klp = &Ks[0][0] + (tid & ~63) * 8;   // wave-uniform base (u16 units)
  const int vn = tid & 63, vd0 = (tid >> 6) * 8;
  const unsigned short* vgp = qkv + (size_t)(rowKV0 + vn) * QKVN + vcol + vd0;

  // ---- Q fragments straight from global ----
  bf16x8 qf[2];
  {
    const unsigned short* qp = qkv + (size_t)(rowQ0 + wave * 16 + l16) * QKVN + qcol + quad * 8;
    qf[0] = *(const bf16x8*)qp;
    qf[1] = *(const bf16x8*)(qp + 32);
  }

  // ---- prologue: stage tile 0 into buffer 0 ----
  u16x8 vreg = *(const u16x8*)vgp;
  gload_lds16(kgp, klp);
  {
    unsigned short* vb = &Vts[0][0];
#pragma unroll
    for (int e = 0; e < 8; ++e)
      vb[(vd0 + e) * VS + vn] = vreg[e];
  }

  f32x4 zero4 = {0.f, 0.f, 0.f, 0.f};
  f32x4 o[4];
#pragma unroll
  for (int dt = 0; dt < 4; ++dt) o[dt] = zero4;
  float lsum = 0.f;

  for (int jt = 0; jt < 16; ++jt) {
    // issue next V global loads early (held in regs through this iteration's compute)
    u16x8 vnext;
    if (jt < 15) vnext = *(const u16x8*)(vgp + (size_t)(jt + 1) * 64 * QKVN);
    __syncthreads();   // buf[jt&1] fully staged; all reads of buf[(jt+1)&1] (from jt-1) done
    if (jt < 15)
      gload_lds16(kgp + (size_t)(jt + 1) * 64 * QKVN, klp + ((jt + 1) & 1) * 4096);  // +4096 u16 = buffer 1

    const unsigned short* Kb = &Ks[jt & 1][0];
    const unsigned short* Vb = &Vts[jt & 1][0];

    // ---- S^T = K Q^T : rows=keys, cols=queries ----
    f32x4 s[4];
#pragma unroll
    for (int nt = 0; nt < 4; ++nt) s[nt] = zero4;
#pragma unroll
    for (int kk = 0; kk < 2; ++kk)
#pragma unroll
      for (int nt = 0; nt < 4; ++nt) {
        bf16x8 kf = *(const bf16x8*)&Kb[kk * 2048 + (nt * 16 + l16) * 32 + quad * 8];
        s[nt] = __builtin_amdgcn_mfma_f32_16x16x32_bf16(kf, qf[kk], s[nt], 0, 0, 0);
      }

    // ---- p = exp(s) in-register; pack to bf16 A-frags; per-lane l partials ----
    s16x4 pf[4];
#pragma unroll
    for (int nt = 0; nt < 4; ++nt)
#pragma unroll
      for (int r = 0; r < 4; ++r) {
        float p = __expf(s[nt][r]);
        lsum += p;
        pf[nt][r] = (short)f2bf(p);
      }

    // ---- O += P V  (P^T regs as A-frag, V^T LDS as B-frag, K=16 chunks) ----
#pragma unroll
    for (int nt = 0; nt < 4; ++nt)
#pragma unroll
      for (int dt = 0; dt < 4; ++dt) {
        s16x4 vv = *(const s16x4*)&Vb[(dt * 16 + l16) * VS + nt * 16 + quad * 4];
        o[dt] = __builtin_amdgcn_mfma_f32_16x16x16bf16_1k(pf[nt], vv, o[dt], 0, 0, 0);
      }

    // ---- sink next V's LDS writes after compute (vmcnt wait overlapped) ----
    if (jt < 15) {
      unsigned short* vb = &Vts[(jt + 1) & 1][0];
#pragma unroll
      for (int e = 0; e < 8; ++e)
        vb[(vd0 + e) * VS + vn] = vnext[e];
    }
  }

  // ---- epilogue: reduce l across quads, redistribute, normalize, store ----
  float l = lsum;
  l += __shfl_xor(l, 16);
  l += __shfl_xor(l, 32);   // full sum for query l16
#pragma unroll
  for (int r = 0; r < 4; ++r) {
    float inv = 1.f / __shfl(l, quad * 4 + r);
    int row = rowQ0 + wave * 16 + quad * 4 + r;
#pragma unroll
    for (int dt = 0; dt < 4; ++dt)
      out[(size_t)row * DIM + h * HD + dt * 16 + l16] = f2bf(o[dt][r] * inv);
  }
}

extern "C" void kernel_launch(void* const* d_in, const int* in_sizes, int n_in,
                              void* d_out, int out_size, void* d_ws, size_t ws_size,
                              hipStream_t stream) {
  const float* x = (const float*)d_in[0];
  const float* w_qkv = (const float*)d_in[1];
  const float* w_proj = (const float*)d_in[2];
  const float* b_proj = (const float*)d_in[3];
  float* outp = (float*)d_out;

  unsigned short* xb = (unsigned short*)d_ws;                     // 8192*768 bf16 (reused as attn out)
  unsigned short* wqkvT = xb + (size_t)ROWS * DIM;                // [2304][768]
  unsigned short* wprojT = wqkvT + (size_t)QKVN * DIM;            // [768][768]
  unsigned short* qkvb = wprojT + (size_t)DIM * DIM;              // [8192][2304]
  unsigned short* attnb = xb;                                     // alias: xb dead after qkv gemm

  prep_kernel<<<dim3(6144 + 1728 + 576), 256, 0, stream>>>(x, xb, w_qkv, wqkvT, w_proj, wprojT);
  // qkv: 64 row-tiles (8/XCD) x 18 col-tiles = 1152 blocks
  gemm_reg<true, true, DIM><<<dim3(1152), 256, 0, stream>>>(xb, wqkvT, qkvb, nullptr, ROWS, QKVN, 8);
  attn_kernel<<<dim3(8 * 96), 512, 0, stream>>>(qkvb, attnb);
  // proj: 64 row-tiles (8/XCD) x 6 col-tiles = 384 blocks
  gemm_reg<false, false, DIM><<<dim3(384), 256, 0, stream>>>(attnb, wprojT, outp, b_proj, ROWS, DIM, 8);
}

// Round 9
// 190.836 us; speedup vs baseline: 1.4763x; 1.4763x over previous
//
#include <hip/hip_runtime.h>
#include <hip/hip_bf16.h>

#define NH 12
#define HD 64
#define SEQ 1024
#define BATCH 8
#define DIM 768
#define QKVN 2304
#define ROWS 8192   // BATCH*SEQ

typedef __bf16 bf16x8 __attribute__((ext_vector_type(8)));
typedef float f32x4 __attribute__((ext_vector_type(4)));
typedef unsigned short u16x8 __attribute__((ext_vector_type(8)));
typedef unsigned short u16x4 __attribute__((ext_vector_type(4)));
typedef short s16x4 __attribute__((ext_vector_type(4)));

__device__ __forceinline__ unsigned short f2bf(float f) {
  union { float f; unsigned int u; } c; c.f = f;
  unsigned int u = c.u;
  u += 0x7fffu + ((u >> 16) & 1u);   // RNE; inputs are normal floats
  return (unsigned short)(u >> 16);
}

__device__ __forceinline__ unsigned int pk_bf16(float a, float b) {
  // packed RNE f32->bf16 pair (v_cvt_pk_bf16_f32 on gfx950)
  union { __hip_bfloat162 h; unsigned int w; } u;
  u.h = __float22bfloat162_rn(float2{a, b});
  return u.w;
}

__device__ __forceinline__ void gload_lds16(const unsigned short* g, unsigned short* l) {
  __builtin_amdgcn_global_load_lds(
      (const __attribute__((address_space(1))) void*)g,
      (__attribute__((address_space(3))) void*)l, 16, 0, 0);
}

// ---------------- fused prep: f32->bf16 cast + both weight transposes ----------------
__device__ __forceinline__ void tr_tile(const float* __restrict__ src, unsigned short* __restrict__ dst,
                                        int R, int C, int bx, int by, float tile[32][33]) {
  int tx = threadIdx.x & 31, ty = threadIdx.x >> 5;   // 32 x 8
  int c0 = bx * 32, r0 = by * 32;
#pragma unroll
  for (int i = 0; i < 4; ++i)
    tile[ty + i * 8][tx] = src[(size_t)(r0 + ty + i * 8) * C + c0 + tx];
  __syncthreads();
#pragma unroll
  for (int i = 0; i < 4; ++i)
    dst[(size_t)(c0 + ty + i * 8) * R + r0 + tx] = f2bf(tile[tx][ty + i * 8]);
}

__global__ void prep_kernel(const float* __restrict__ x, unsigned short* __restrict__ xb,
                            const float* __restrict__ w_qkv, unsigned short* __restrict__ wqkvT,
                            const float* __restrict__ w_proj, unsigned short* __restrict__ wprojT) {
  __shared__ float tile[32][33];
  int blk = blockIdx.x;
  if (blk < 6144) {
    int i = blk * 256 + threadIdx.x;   // n4 = 8192*768/4 = 1572864 = 6144*256 exactly
    float4 v = ((const float4*)x)[i];
    unsigned int lo = pk_bf16(v.x, v.y), hi = pk_bf16(v.z, v.w);
    union { unsigned int w[2]; u16x4 o; } u; u.w[0] = lo; u.w[1] = hi;
    ((u16x4*)xb)[i] = u.o;
  } else if (blk < 6144 + 1728) {
    int t = blk - 6144;                // w_qkv: 768x2304 -> 24 x 72 tiles
    tr_tile(w_qkv, wqkvT, DIM, QKVN, t % 72, t / 72, tile);
  } else {
    int t = blk - 6144 - 1728;         // w_proj: 768x768 -> 24 x 24 tiles
    tr_tile(w_proj, wprojT, DIM, DIM, t % 24, t / 24, tile);
  }
}

// ---------------- 128x128 bf16 GEMM, BT input; double-buffered, 1 barrier/K-iter ----
// R6 structure (best measured: qkv 49.9 us, 557 TF). XCD-banded rows; DMA prefetch
// issued right after the barrier, drained one compute phase later. launch_bounds(256,4)
// = 128-reg budget: acc(64)+addr fits with NO spills ((256,5) spilled: R5 +6.7MB WRITE).
// R8 lesson: register-direct fragment loads are TA-bound (16 lines/instr) — keep DMA.
template <bool BF16_OUT, bool SCALE_Q>
__global__ __launch_bounds__(256, 4) void gemm128(
    const unsigned short* __restrict__ A, const unsigned short* __restrict__ BT,
    void* __restrict__ Cout, const float* __restrict__ bias,
    int M, int N, int K, int nbyXCD) {
  __shared__ unsigned short As[2][128 * 32];
  __shared__ unsigned short Bs[2][128 * 32];
  const int tid = threadIdx.x;
  const int wave = tid >> 6, lane = tid & 63, quad = lane >> 4, l16 = lane & 15;
  const int wm = wave >> 1, wn = wave & 1;
  const int g = blockIdx.x & 7, bi = blockIdx.x >> 3;
  const int by = g * nbyXCD + (bi % nbyXCD);
  const int bx = bi / nbyXCD;
  const int bm = by * 128, bn = bx * 128;

  const int r0 = tid >> 2, kc0 = (tid & 3) * 8;
  const unsigned short* Ag = A + (size_t)(bm + r0) * K + kc0;
  const unsigned short* Bg = BT + (size_t)(bn + r0) * K + kc0;
  unsigned short* AsB = &As[0][0];
  unsigned short* BsB = &Bs[0][0];
  const int wdst = (tid & ~63) * 8;   // wave-uniform LDS chunk base (u16)

#define STAGE_G(kt, b) do {                                                   \
    int koff_ = (kt) * 32;                                                    \
    gload_lds16(Ag + koff_,                    AsB + (b) * 4096 + wdst);      \
    gload_lds16(Ag + koff_ + (size_t)64 * K,   AsB + (b) * 4096 + wdst + 2048);\
    gload_lds16(Bg + koff_,                    BsB + (b) * 4096 + wdst);      \
    gload_lds16(Bg + koff_ + (size_t)64 * K,   BsB + (b) * 4096 + wdst + 2048);\
  } while (0)

  f32x4 zero4 = {0.f, 0.f, 0.f, 0.f};
  f32x4 acc[4][4];
#pragma unroll
  for (int i = 0; i < 4; ++i)
#pragma unroll
    for (int j = 0; j < 4; ++j) acc[i][j] = zero4;

  const int nkt = K >> 5;
  STAGE_G(0, 0);   // prologue: tile 0 -> buf 0
  for (int kt = 0; kt < nkt; ++kt) {
    __syncthreads();   // buf[kt&1] staged; reads of buf[(kt+1)&1] from kt-1 done
    if (kt + 1 < nkt) STAGE_G(kt + 1, (kt + 1) & 1);
    const unsigned short* Ab = AsB + (kt & 1) * 4096;
    const unsigned short* Bb = BsB + (kt & 1) * 4096;
    bf16x8 af[4], bf[4];
#pragma unroll
    for (int mt = 0; mt < 4; ++mt)
      af[mt] = *(const bf16x8*)&Ab[(wm * 64 + mt * 16 + l16) * 32 + quad * 8];
#pragma unroll
    for (int nt = 0; nt < 4; ++nt)
      bf[nt] = *(const bf16x8*)&Bb[(wn * 64 + nt * 16 + l16) * 32 + quad * 8];
#pragma unroll
    for (int mt = 0; mt < 4; ++mt)
#pragma unroll
      for (int nt = 0; nt < 4; ++nt)
        acc[mt][nt] = __builtin_amdgcn_mfma_f32_16x16x32_bf16(af[mt], bf[nt], acc[mt][nt], 0, 0, 0);
  }
#undef STAGE_G

#pragma unroll
  for (int mt = 0; mt < 4; ++mt)
#pragma unroll
    for (int nt = 0; nt < 4; ++nt) {
      int col = bn + wn * 64 + nt * 16 + l16;
      float bv = BF16_OUT ? 0.f : bias[col];
      float scl = (SCALE_Q && col < DIM) ? 0.125f : 1.0f;  // fold attn scale into q
#pragma unroll
      for (int r = 0; r < 4; ++r) {
        int row = bm + wm * 64 + mt * 16 + quad * 4 + r;
        float v = acc[mt][nt][r];
        if (BF16_OUT)
          ((unsigned short*)Cout)[(size_t)row * N + col] = f2bf(v * scl);
        else
          ((float*)Cout)[(size_t)row * N + col] = v + bv;
      }
    }
}

// ---------------- flash attention: Q-tile 128 (8 waves), KV-tile 64 ----------------
// S^T trick: scores computed transposed so exp(P) feeds PV directly from registers
// (C-layout [key=quad*4+r][query=l16] == A-frag of mfma_f32_16x16x16bf16_1k).
// Double-buffered K (DMA) + V (reg-held loads, LDS write sunk after compute): 1 barrier/jt.
// P repack via v_cvt_pk_bf16_f32 (packed RNE) — 1 inst/2 vals vs ~4 VALU/val scalar.
#define VS 76   // Vts row stride (u16): 38 dwords == 6 mod 32 -> ~2-way (free) on b64 reads
__global__ __launch_bounds__(512, 6) void attn_kernel(
    const unsigned short* __restrict__ qkv, unsigned short* __restrict__ out) {
  __shared__ unsigned short Ks[2][64 * 64];     // [kk][n][32] split layout per buffer, 8 KB each
  __shared__ unsigned short Vts[2][64 * VS];    // V^T [d][n], 9.5 KB each

  const int tid = threadIdx.x;
  const int wave = tid >> 6, lane = tid & 63, quad = lane >> 4, l16 = lane & 15;
  // XCD-locality swizzle: all 8 q-tiles of one (b,h) share id%8 -> same XCD
  const int x = blockIdx.x;
  const int qt = (x >> 3) & 7;
  const int bh = (x & 7) + 8 * (x >> 6);
  const int b = bh / NH, h = bh % NH;
  const int qcol = h * HD, kcol = DIM + h * HD, vcol = 2 * DIM + h * HD;
  const int rowQ0 = b * SEQ + qt * 128;
  const int rowKV0 = b * SEQ;

  // staging index precompute
  const int kk_s = tid >> 8, rem_s = tid & 255, n_s = rem_s >> 2, kc_s = rem_s & 3;
  const unsigned short* kgp = qkv + (size_t)(rowKV0 + n_s) * QKVN + kcol + kk_s * 32 + kc_s * 8;
  unsigned short* klp = &Ks[0][0] + (tid & ~63) * 8;   // wave-uniform base (u16 units)
  const int vn = tid & 63, vd0 = (tid >> 6) * 8;
  const unsigned short* vgp = qkv + (size_t)(rowKV0 + vn) * QKVN + vcol + vd0;

  // ---- Q fragments straight from global ----
  bf16x8 qf[2];
  {
    const unsigned short* qp = qkv + (size_t)(rowQ0 + wave * 16 + l16) * QKVN + qcol + quad * 8;
    qf[0] = *(const bf16x8*)qp;
    qf[1] = *(const bf16x8*)(qp + 32);
  }

  // ---- prologue: stage tile 0 into buffer 0 ----
  u16x8 vreg = *(const u16x8*)vgp;
  gload_lds16(kgp, klp);
  {
    unsigned short* vb = &Vts[0][0];
#pragma unroll
    for (int e = 0; e < 8; ++e)
      vb[(vd0 + e) * VS + vn] = vreg[e];
  }

  f32x4 zero4 = {0.f, 0.f, 0.f, 0.f};
  f32x4 o[4];
#pragma unroll
  for (int dt = 0; dt < 4; ++dt) o[dt] = zero4;
  float lsum = 0.f;

  for (int jt = 0; jt < 16; ++jt) {
    // issue next V global loads early (held in regs through this iteration's compute)
    u16x8 vnext;
    if (jt < 15) vnext = *(const u16x8*)(vgp + (size_t)(jt + 1) * 64 * QKVN);
    __syncthreads();   // buf[jt&1] fully staged; all reads of buf[(jt+1)&1] (from jt-1) done
    if (jt < 15)
      gload_lds16(kgp + (size_t)(jt + 1) * 64 * QKVN, klp + ((jt + 1) & 1) * 4096);  // +4096 u16 = buffer 1

    const unsigned short* Kb = &Ks[jt & 1][0];
    const unsigned short* Vb = &Vts[jt & 1][0];

    // ---- S^T = K Q^T : rows=keys, cols=queries ----
    f32x4 s[4];
#pragma unroll
    for (int nt = 0; nt < 4; ++nt) s[nt] = zero4;
#pragma unroll
    for (int kk = 0; kk < 2; ++kk)
#pragma unroll
      for (int nt = 0; nt < 4; ++nt) {
        bf16x8 kf = *(const bf16x8*)&Kb[kk * 2048 + (nt * 16 + l16) * 32 + quad * 8];
        s[nt] = __builtin_amdgcn_mfma_f32_16x16x32_bf16(kf, qf[kk], s[nt], 0, 0, 0);
      }

    // ---- p = exp(s); packed cvt to bf16 A-frags; per-lane l partials ----
    s16x4 pf[4];
#pragma unroll
    for (int nt = 0; nt < 4; ++nt) {
      float p0 = __expf(s[nt][0]);
      float p1 = __expf(s[nt][1]);
      float p2 = __expf(s[nt][2]);
      float p3 = __expf(s[nt][3]);
      lsum += (p0 + p1) + (p2 + p3);
      union { unsigned int w[2]; s16x4 v; } u;
      u.w[0] = pk_bf16(p0, p1);
      u.w[1] = pk_bf16(p2, p3);
      pf[nt] = u.v;
    }

    // ---- O += P V  (P^T regs as A-frag, V^T LDS as B-frag, K=16 chunks) ----
#pragma unroll
    for (int nt = 0; nt < 4; ++nt)
#pragma unroll
      for (int dt = 0; dt < 4; ++dt) {
        s16x4 vv = *(const s16x4*)&Vb[(dt * 16 + l16) * VS + nt * 16 + quad * 4];
        o[dt] = __builtin_amdgcn_mfma_f32_16x16x16bf16_1k(pf[nt], vv, o[dt], 0, 0, 0);
      }

    // ---- sink next V's LDS writes after compute (vmcnt wait overlapped) ----
    if (jt < 15) {
      unsigned short* vb = &Vts[(jt + 1) & 1][0];
#pragma unroll
      for (int e = 0; e < 8; ++e)
        vb[(vd0 + e) * VS + vn] = vnext[e];
    }
  }

  // ---- epilogue: reduce l across quads, redistribute, normalize, store ----
  float l = lsum;
  l += __shfl_xor(l, 16);
  l += __shfl_xor(l, 32);   // full sum for query l16
#pragma unroll
  for (int r = 0; r < 4; ++r) {
    float inv = 1.f / __shfl(l, quad * 4 + r);
    int row = rowQ0 + wave * 16 + quad * 4 + r;
#pragma unroll
    for (int dt = 0; dt < 4; ++dt)
      out[(size_t)row * DIM + h * HD + dt * 16 + l16] = f2bf(o[dt][r] * inv);
  }
}

extern "C" void kernel_launch(void* const* d_in, const int* in_sizes, int n_in,
                              void* d_out, int out_size, void* d_ws, size_t ws_size,
                              hipStream_t stream) {
  const float* x = (const float*)d_in[0];
  const float* w_qkv = (const float*)d_in[1];
  const float* w_proj = (const float*)d_in[2];
  const float* b_proj = (const float*)d_in[3];
  float* outp = (float*)d_out;

  unsigned short* xb = (unsigned short*)d_ws;                     // 8192*768 bf16 (reused as attn out)
  unsigned short* wqkvT = xb + (size_t)ROWS * DIM;                // [2304][768]
  unsigned short* wprojT = wqkvT + (size_t)QKVN * DIM;            // [768][768]
  unsigned short* qkvb = wprojT + (size_t)DIM * DIM;              // [8192][2304]
  unsigned short* attnb = xb;                                     // alias: xb dead after qkv gemm

  prep_kernel<<<dim3(6144 + 1728 + 576), 256, 0, stream>>>(x, xb, w_qkv, wqkvT, w_proj, wprojT);
  // qkv: 64 row-tiles (8/XCD) x 18 col-tiles = 1152 blocks
  gemm128<true, true><<<dim3(1152), 256, 0, stream>>>(xb, wqkvT, qkvb, nullptr, ROWS, QKVN, DIM, 8);
  attn_kernel<<<dim3(8 * 96), 512, 0, stream>>>(qkvb, attnb);
  // proj: 64 row-tiles (8/XCD) x 6 col-tiles = 384 blocks
  gemm128<false, false><<<dim3(384), 256, 0, stream>>>(attnb, wprojT, outp, b_proj, ROWS, DIM, DIM, 8);
}

// Round 10
// 186.112 us; speedup vs baseline: 1.5138x; 1.0254x over previous
//
#include <hip/hip_runtime.h>
#include <hip/hip_bf16.h>

#define NH 12
#define HD 64
#define SEQ 1024
#define BATCH 8
#define DIM 768
#define QKVN 2304
#define ROWS 8192   // BATCH*SEQ

typedef __bf16 bf16x8 __attribute__((ext_vector_type(8)));
typedef float f32x4 __attribute__((ext_vector_type(4)));
typedef unsigned short u16x8 __attribute__((ext_vector_type(8)));
typedef unsigned short u16x4 __attribute__((ext_vector_type(4)));
typedef short s16x4 __attribute__((ext_vector_type(4)));

__device__ __forceinline__ unsigned short f2bf(float f) {
  union { float f; unsigned int u; } c; c.f = f;
  unsigned int u = c.u;
  u += 0x7fffu + ((u >> 16) & 1u);   // RNE; inputs are normal floats
  return (unsigned short)(u >> 16);
}

__device__ __forceinline__ unsigned int pk_bf16(float a, float b) {
  // packed RNE f32->bf16 pair (v_cvt_pk_bf16_f32 on gfx950)
  union { __hip_bfloat162 h; unsigned int w; } u;
  u.h = __float22bfloat162_rn(float2{a, b});
  return u.w;
}

__device__ __forceinline__ void gload_lds16(const unsigned short* g, unsigned short* l) {
  __builtin_amdgcn_global_load_lds(
      (const __attribute__((address_space(1))) void*)g,
      (__attribute__((address_space(3))) void*)l, 16, 0, 0);
}

// ---------------- fused prep: f32->bf16 cast + both weight transposes ----------------
__device__ __forceinline__ void tr_tile(const float* __restrict__ src, unsigned short* __restrict__ dst,
                                        int R, int C, int bx, int by, float tile[32][33]) {
  int tx = threadIdx.x & 31, ty = threadIdx.x >> 5;   // 32 x 8
  int c0 = bx * 32, r0 = by * 32;
#pragma unroll
  for (int i = 0; i < 4; ++i)
    tile[ty + i * 8][tx] = src[(size_t)(r0 + ty + i * 8) * C + c0 + tx];
  __syncthreads();
#pragma unroll
  for (int i = 0; i < 4; ++i)
    dst[(size_t)(c0 + ty + i * 8) * R + r0 + tx] = f2bf(tile[tx][ty + i * 8]);
}

__global__ void prep_kernel(const float* __restrict__ x, unsigned short* __restrict__ xb,
                            const float* __restrict__ w_qkv, unsigned short* __restrict__ wqkvT,
                            const float* __restrict__ w_proj, unsigned short* __restrict__ wprojT) {
  __shared__ float tile[32][33];
  int blk = blockIdx.x;
  if (blk < 6144) {
    int i = blk * 256 + threadIdx.x;   // n4 = 8192*768/4 = 1572864 = 6144*256 exactly
    float4 v = ((const float4*)x)[i];
    unsigned int lo = pk_bf16(v.x, v.y), hi = pk_bf16(v.z, v.w);
    union { unsigned int w[2]; u16x4 o; } u; u.w[0] = lo; u.w[1] = hi;
    ((u16x4*)xb)[i] = u.o;
  } else if (blk < 6144 + 1728) {
    int t = blk - 6144;                // w_qkv: 768x2304 -> 24 x 72 tiles
    tr_tile(w_qkv, wqkvT, DIM, QKVN, t % 72, t / 72, tile);
  } else {
    int t = blk - 6144 - 1728;         // w_proj: 768x768 -> 24 x 24 tiles
    tr_tile(w_proj, wprojT, DIM, DIM, t % 24, t / 24, tile);
  }
}

// ---------------- 128x128 bf16 GEMM (qkv), dbuf, 1 barrier/K-iter ----------------
// Barrier audit clean: STAGE issued post-barrier -> at next barrier all outstanding
// DMAs are one full compute phase old. launch_bounds(256,4): no spills (R5 lesson).
template <bool BF16_OUT, bool SCALE_Q>
__global__ __launch_bounds__(256, 4) void gemm128(
    const unsigned short* __restrict__ A, const unsigned short* __restrict__ BT,
    void* __restrict__ Cout, const float* __restrict__ bias,
    int M, int N, int K, int nbyXCD) {
  __shared__ unsigned short As[2][128 * 32];
  __shared__ unsigned short Bs[2][128 * 32];
  const int tid = threadIdx.x;
  const int wave = tid >> 6, lane = tid & 63, quad = lane >> 4, l16 = lane & 15;
  const int wm = wave >> 1, wn = wave & 1;
  const int g = blockIdx.x & 7, bi = blockIdx.x >> 3;
  const int by = g * nbyXCD + (bi % nbyXCD);
  const int bx = bi / nbyXCD;
  const int bm = by * 128, bn = bx * 128;

  const int r0 = tid >> 2, kc0 = (tid & 3) * 8;
  const unsigned short* Ag = A + (size_t)(bm + r0) * K + kc0;
  const unsigned short* Bg = BT + (size_t)(bn + r0) * K + kc0;
  unsigned short* AsB = &As[0][0];
  unsigned short* BsB = &Bs[0][0];
  const int wdst = (tid & ~63) * 8;   // wave-uniform LDS chunk base (u16)

#define STAGE_G(kt, b) do {                                                   \
    int koff_ = (kt) * 32;                                                    \
    gload_lds16(Ag + koff_,                    AsB + (b) * 4096 + wdst);      \
    gload_lds16(Ag + koff_ + (size_t)64 * K,   AsB + (b) * 4096 + wdst + 2048);\
    gload_lds16(Bg + koff_,                    BsB + (b) * 4096 + wdst);      \
    gload_lds16(Bg + koff_ + (size_t)64 * K,   BsB + (b) * 4096 + wdst + 2048);\
  } while (0)

  f32x4 zero4 = {0.f, 0.f, 0.f, 0.f};
  f32x4 acc[4][4];
#pragma unroll
  for (int i = 0; i < 4; ++i)
#pragma unroll
    for (int j = 0; j < 4; ++j) acc[i][j] = zero4;

  const int nkt = K >> 5;
  STAGE_G(0, 0);   // prologue: tile 0 -> buf 0
  for (int kt = 0; kt < nkt; ++kt) {
    __syncthreads();   // buf[kt&1] staged; reads of buf[(kt+1)&1] from kt-1 done
    if (kt + 1 < nkt) STAGE_G(kt + 1, (kt + 1) & 1);
    const unsigned short* Ab = AsB + (kt & 1) * 4096;
    const unsigned short* Bb = BsB + (kt & 1) * 4096;
    bf16x8 af[4], bf[4];
#pragma unroll
    for (int mt = 0; mt < 4; ++mt)
      af[mt] = *(const bf16x8*)&Ab[(wm * 64 + mt * 16 + l16) * 32 + quad * 8];
#pragma unroll
    for (int nt = 0; nt < 4; ++nt)
      bf[nt] = *(const bf16x8*)&Bb[(wn * 64 + nt * 16 + l16) * 32 + quad * 8];
#pragma unroll
    for (int mt = 0; mt < 4; ++mt)
#pragma unroll
      for (int nt = 0; nt < 4; ++nt)
        acc[mt][nt] = __builtin_amdgcn_mfma_f32_16x16x32_bf16(af[mt], bf[nt], acc[mt][nt], 0, 0, 0);
  }
#undef STAGE_G

#pragma unroll
  for (int mt = 0; mt < 4; ++mt)
#pragma unroll
    for (int nt = 0; nt < 4; ++nt) {
      int col = bn + wn * 64 + nt * 16 + l16;
      float bv = BF16_OUT ? 0.f : bias[col];
      float scl = (SCALE_Q && col < DIM) ? 0.125f : 1.0f;  // fold attn scale into q
#pragma unroll
      for (int r = 0; r < 4; ++r) {
        int row = bm + wm * 64 + mt * 16 + quad * 4 + r;
        float v = acc[mt][nt][r];
        if (BF16_OUT)
          ((unsigned short*)Cout)[(size_t)row * N + col] = f2bf(v * scl);
        else
          ((float*)Cout)[(size_t)row * N + col] = v + bv;
      }
    }
}

// ---------------- 128x64 bf16 GEMM for proj: 768 blocks = 3/CU (vs 1.5 at 128x128) ----
// proj is occupancy-bound at 384 blocks; narrow tile doubles block count. Spill-free
// at (256,5): R7 measured VGPR 40, WRITE unchanged.
__global__ __launch_bounds__(256, 5) void gemm64_proj(
    const unsigned short* __restrict__ A, const unsigned short* __restrict__ BT,
    float* __restrict__ Cout, const float* __restrict__ bias,
    int M, int N, int K, int nbyXCD) {
  __shared__ unsigned short As[2][128 * 32];
  __shared__ unsigned short Bs[2][64 * 32];
  const int tid = threadIdx.x;
  const int wave = tid >> 6, lane = tid & 63, quad = lane >> 4, l16 = lane & 15;
  const int g = blockIdx.x & 7, bi = blockIdx.x >> 3;
  const int by = g * nbyXCD + (bi % nbyXCD);
  const int bx = bi / nbyXCD;
  const int bm = by * 128, bn = bx * 64;

  const int r0 = tid >> 2, kc0 = (tid & 3) * 8;
  const unsigned short* Ag = A + (size_t)(bm + r0) * K + kc0;
  const unsigned short* Bg = BT + (size_t)(bn + r0) * K + kc0;
  unsigned short* AsB = &As[0][0];
  unsigned short* BsB = &Bs[0][0];
  const int wdst = (tid & ~63) * 8;

#define STAGE_P(kt, b) do {                                                    \
    int koff_ = (kt) * 32;                                                     \
    gload_lds16(Ag + koff_,                  AsB + (b) * 4096 + wdst);         \
    gload_lds16(Ag + koff_ + (size_t)64 * K, AsB + (b) * 4096 + wdst + 2048);  \
    gload_lds16(Bg + koff_,                  BsB + (b) * 2048 + wdst);         \
  } while (0)

  f32x4 zero4 = {0.f, 0.f, 0.f, 0.f};
  f32x4 acc[2][4];
#pragma unroll
  for (int i = 0; i < 2; ++i)
#pragma unroll
    for (int j = 0; j < 4; ++j) acc[i][j] = zero4;

  const int nkt = K >> 5;
  STAGE_P(0, 0);
  for (int kt = 0; kt < nkt; ++kt) {
    __syncthreads();
    if (kt + 1 < nkt) STAGE_P(kt + 1, (kt + 1) & 1);
    const unsigned short* Ab = AsB + (kt & 1) * 4096;
    const unsigned short* Bb = BsB + (kt & 1) * 2048;
    bf16x8 af[2], bf[4];
#pragma unroll
    for (int mt = 0; mt < 2; ++mt)
      af[mt] = *(const bf16x8*)&Ab[(wave * 32 + mt * 16 + l16) * 32 + quad * 8];
#pragma unroll
    for (int nt = 0; nt < 4; ++nt)
      bf[nt] = *(const bf16x8*)&Bb[(nt * 16 + l16) * 32 + quad * 8];
#pragma unroll
    for (int mt = 0; mt < 2; ++mt)
#pragma unroll
      for (int nt = 0; nt < 4; ++nt)
        acc[mt][nt] = __builtin_amdgcn_mfma_f32_16x16x32_bf16(af[mt], bf[nt], acc[mt][nt], 0, 0, 0);
  }
#undef STAGE_P

#pragma unroll
  for (int mt = 0; mt < 2; ++mt)
#pragma unroll
    for (int nt = 0; nt < 4; ++nt) {
      int col = bn + nt * 16 + l16;
      float bv = bias[col];
#pragma unroll
      for (int r = 0; r < 4; ++r) {
        int row = bm + wave * 32 + mt * 16 + quad * 4 + r;
        Cout[(size_t)row * N + col] = acc[mt][nt][r] + bv;
      }
    }
}

// ---------------- flash attention: Q-tile 128 (8 waves), KV-tile 64 ----------------
// S^T trick + reg-fed PV (16x16x16bf16_1k). BARRIER-DRAIN FIX (R10): the vnext V
// global-load is now issued AFTER __syncthreads (next to the K-DMA). Previously it
// was issued just before the barrier, and __syncthreads' vmcnt(0) drain exposed its
// full L2 latency every jt. Now every VMEM op outstanding at a barrier is one full
// compute phase old -> the drain is free.
#define VS 76   // Vts row stride (u16)
__global__ __launch_bounds__(512, 6) void attn_kernel(
    const unsigned short* __restrict__ qkv, unsigned short* __restrict__ out) {
  __shared__ unsigned short Ks[2][64 * 64];     // [kk][n][32] split layout per buffer, 8 KB each
  __shared__ unsigned short Vts[2][64 * VS];    // V^T [d][n], 9.5 KB each

  const int tid = threadIdx.x;
  const int wave = tid >> 6, lane = tid & 63, quad = lane >> 4, l16 = lane & 15;
  // XCD-locality swizzle: all 8 q-tiles of one (b,h) share id%8 -> same XCD
  const int x = blockIdx.x;
  const int qt = (x >> 3) & 7;
  const int bh = (x & 7) + 8 * (x >> 6);
  const int b = bh / NH, h = bh % NH;
  const int qcol = h * HD, kcol = DIM + h * HD, vcol = 2 * DIM + h * HD;
  const int rowQ0 = b * SEQ + qt * 128;
  const int rowKV0 = b * SEQ;

  // staging index precompute
  const int kk_s = tid >> 8, rem_s = tid & 255, n_s = rem_s >> 2, kc_s = rem_s & 3;
  const unsigned short* kgp = qkv + (size_t)(rowKV0 + n_s) * QKVN + kcol + kk_s * 32 + kc_s * 8;
  unsigned short* klp = &Ks[0][0] + (tid & ~63) * 8;   // wave-uniform base (u16 units)
  const int vn = tid & 63, vd0 = (tid >> 6) * 8;
  const unsigned short* vgp = qkv + (size_t)(rowKV0 + vn) * QKVN + vcol + vd0;

  // ---- Q fragments straight from global ----
  bf16x8 qf[2];
  {
    const unsigned short* qp = qkv + (size_t)(rowQ0 + wave * 16 + l16) * QKVN + qcol + quad * 8;
    qf[0] = *(const bf16x8*)qp;
    qf[1] = *(const bf16x8*)(qp + 32);
  }

  // ---- prologue: stage tile 0 into buffer 0 ----
  gload_lds16(kgp, klp);
  {
    u16x8 v0 = *(const u16x8*)vgp;
    unsigned short* vb = &Vts[0][0];
#pragma unroll
    for (int e = 0; e < 8; ++e)
      vb[(vd0 + e) * VS + vn] = v0[e];
  }

  f32x4 zero4 = {0.f, 0.f, 0.f, 0.f};
  f32x4 o[4];
#pragma unroll
  for (int dt = 0; dt < 4; ++dt) o[dt] = zero4;
  float lsum = 0.f;

  for (int jt = 0; jt < 16; ++jt) {
    __syncthreads();   // drains K-DMA(jt) + vload(jt): both one compute phase old
    u16x8 vnext;
    if (jt < 15) {
      gload_lds16(kgp + (size_t)(jt + 1) * 64 * QKVN, klp + ((jt + 1) & 1) * 4096);
      vnext = *(const u16x8*)(vgp + (size_t)(jt + 1) * 64 * QKVN);
    }

    const unsigned short* Kb = &Ks[jt & 1][0];
    const unsigned short* Vb = &Vts[jt & 1][0];

    // ---- S^T = K Q^T : rows=keys, cols=queries ----
    f32x4 s[4];
#pragma unroll
    for (int nt = 0; nt < 4; ++nt) s[nt] = zero4;
#pragma unroll
    for (int kk = 0; kk < 2; ++kk)
#pragma unroll
      for (int nt = 0; nt < 4; ++nt) {
        bf16x8 kf = *(const bf16x8*)&Kb[kk * 2048 + (nt * 16 + l16) * 32 + quad * 8];
        s[nt] = __builtin_amdgcn_mfma_f32_16x16x32_bf16(kf, qf[kk], s[nt], 0, 0, 0);
      }

    // ---- p = exp(s); packed cvt to bf16 A-frags; per-lane l partials ----
    s16x4 pf[4];
#pragma unroll
    for (int nt = 0; nt < 4; ++nt) {
      float p0 = __expf(s[nt][0]);
      float p1 = __expf(s[nt][1]);
      float p2 = __expf(s[nt][2]);
      float p3 = __expf(s[nt][3]);
      lsum += (p0 + p1) + (p2 + p3);
      union { unsigned int w[2]; s16x4 v; } u;
      u.w[0] = pk_bf16(p0, p1);
      u.w[1] = pk_bf16(p2, p3);
      pf[nt] = u.v;
    }

    // ---- O += P V  (P^T regs as A-frag, V^T LDS as B-frag, K=16 chunks) ----
#pragma unroll
    for (int nt = 0; nt < 4; ++nt)
#pragma unroll
      for (int dt = 0; dt < 4; ++dt) {
        s16x4 vv = *(const s16x4*)&Vb[(dt * 16 + l16) * VS + nt * 16 + quad * 4];
        o[dt] = __builtin_amdgcn_mfma_f32_16x16x16bf16_1k(pf[nt], vv, o[dt], 0, 0, 0);
      }

    // ---- sink next V's LDS writes after compute (vnext is compute-phase old) ----
    if (jt < 15) {
      unsigned short* vb = &Vts[(jt + 1) & 1][0];
#pragma unroll
      for (int e = 0; e < 8; ++e)
        vb[(vd0 + e) * VS + vn] = vnext[e];
    }
  }

  // ---- epilogue: reduce l across quads, redistribute, normalize, store ----
  float l = lsum;
  l += __shfl_xor(l, 16);
  l += __shfl_xor(l, 32);   // full sum for query l16
#pragma unroll
  for (int r = 0; r < 4; ++r) {
    float inv = 1.f / __shfl(l, quad * 4 + r);
    int row = rowQ0 + wave * 16 + quad * 4 + r;
#pragma unroll
    for (int dt = 0; dt < 4; ++dt)
      out[(size_t)row * DIM + h * HD + dt * 16 + l16] = f2bf(o[dt][r] * inv);
  }
}

extern "C" void kernel_launch(void* const* d_in, const int* in_sizes, int n_in,
                              void* d_out, int out_size, void* d_ws, size_t ws_size,
                              hipStream_t stream) {
  const float* x = (const float*)d_in[0];
  const float* w_qkv = (const float*)d_in[1];
  const float* w_proj = (const float*)d_in[2];
  const float* b_proj = (const float*)d_in[3];
  float* outp = (float*)d_out;

  unsigned short* xb = (unsigned short*)d_ws;                     // 8192*768 bf16 (reused as attn out)
  unsigned short* wqkvT = xb + (size_t)ROWS * DIM;                // [2304][768]
  unsigned short* wprojT = wqkvT + (size_t)QKVN * DIM;            // [768][768]
  unsigned short* qkvb = wprojT + (size_t)DIM * DIM;              // [8192][2304]
  unsigned short* attnb = xb;                                     // alias: xb dead after qkv gemm

  prep_kernel<<<dim3(6144 + 1728 + 576), 256, 0, stream>>>(x, xb, w_qkv, wqkvT, w_proj, wprojT);
  // qkv: 64 row-tiles (8/XCD) x 18 col-tiles = 1152 blocks
  gemm128<true, true><<<dim3(1152), 256, 0, stream>>>(xb, wqkvT, qkvb, nullptr, ROWS, QKVN, DIM, 8);
  attn_kernel<<<dim3(8 * 96), 512, 0, stream>>>(qkvb, attnb);
  // proj: 64 row-tiles (8/XCD) x 12 col-tiles of 64 = 768 blocks (3/CU)
  gemm64_proj<<<dim3(768), 256, 0, stream>>>(attnb, wprojT, outp, b_proj, ROWS, DIM, DIM, 8);
}